// Round 4
// baseline (72.795 us; speedup 1.0000x reference)
//
#include <hip/hip_runtime.h>

// SeeSawLoss, simplified:
//   loss(b,h,w) = log( sum_i exp(l[b,i,h,w]) * max(w[b,i], w[b,t]) ) - log(w[b,t]) - l[b,t,h,w]
//   out = mean over all (b,h,w)
// since M[i,t] = (wi > wt ? wi/wt : 1) == max(wi, wt)/wt.
// B=8, N=128, H=W=128.
//
// R3 ladder showed latency-bound monotone gain with waves/CU (2->23.7us,
// 8->20.3, 16->18.4). This round: 32 waves/CU (HW cap) via 8-way class split,
// plus fused final reduction (atomic + completion counter) to drop the second
// dispatch.

#define B_    8
#define N_    128
#define HW_   16384              // 128*128
#define NPIX  (B_ * HW_)         // 131072
#define BLOCK 512                // 8 waves
#define OCTS  8                  // class octants (16 classes each)
#define E_    16                 // classes per thread
#define PX    64                 // pixels per block
#define BLOCKS_PER_B (HW_ / PX)  // 256
#define NBLOCKS (B_ * BLOCKS_PER_B)  // 2048

__global__ __launch_bounds__(BLOCK, 8) void seesaw_main(
    const float* __restrict__ logit,
    const int*   __restrict__ target,
    const float* __restrict__ weight,
    float*       __restrict__ acc,      // d_ws[0]: running sum (memset 0 per call)
    unsigned int* __restrict__ cnt,     // d_ws[1]: completion counter
    float*       __restrict__ out)
{
    __shared__ float w_s[N_];
    __shared__ float sa[OCTS][PX];
    __shared__ float sl[OCTS][PX];

    const int b    = blockIdx.x >> 8;            // / BLOCKS_PER_B
    const int pix0 = (blockIdx.x & 255) * PX;
    const int pl   = threadIdx.x & 63;           // pixel-local
    const int oct  = threadIdx.x >> 6;           // class octant
    const int pix  = pix0 + pl;

    if (threadIdx.x < N_) w_s[threadIdx.x] = weight[b * N_ + threadIdx.x];
    __syncthreads();

    const int   t  = target[b * HW_ + pix];
    const float wt = w_s[t];

    const int ibase = oct * E_;
    const float* lp = logit + (size_t)(b * N_ + ibase) * HW_ + pix;

    float a  = 0.0f;
    float lt = 0.0f;

    #pragma unroll 8
    for (int k = 0; k < E_; ++k) {
        const float l  = lp[(size_t)k * HW_];
        const float wi = w_s[ibase + k];
        a  = fmaf(__expf(l), fmaxf(wi, wt), a);
        lt = (ibase + k == t) ? l : lt;
    }

    sa[oct][pl] = a;
    sl[oct][pl] = lt;
    __syncthreads();

    float loss = 0.0f;
    if (oct == 0) {
        float at = 0.0f, lf = 0.0f;
        #pragma unroll
        for (int k = 0; k < OCTS; ++k) { at += sa[k][pl]; lf += sl[k][pl]; }
        loss = __logf(at) - __logf(wt) - lf;

        // single-wave reduction over the 64 pixels
        #pragma unroll
        for (int o = 32; o > 0; o >>= 1) loss += __shfl_down(loss, o, 64);
    }

    if (threadIdx.x == 0) {
        atomicAdd(acc, loss);
        __threadfence();
        const unsigned int old = atomicAdd(cnt, 1u);
        if (old == NBLOCKS - 1) {
            const float total = atomicAdd(acc, 0.0f);   // coherent read of final sum
            out[0] = total * (1.0f / (float)NPIX);
        }
    }
}

extern "C" void kernel_launch(void* const* d_in, const int* in_sizes, int n_in,
                              void* d_out, int out_size, void* d_ws, size_t ws_size,
                              hipStream_t stream)
{
    const float* logit  = (const float*)d_in[0];
    const int*   target = (const int*)  d_in[1];
    const float* weight = (const float*)d_in[2];
    // d_in[3] = epoch (unused by the reference math)

    float*        acc = (float*)d_ws;
    unsigned int* cnt = (unsigned int*)((char*)d_ws + sizeof(float));
    float*        out = (float*)d_out;

    hipMemsetAsync(d_ws, 0, 2 * sizeof(float), stream);
    seesaw_main<<<NBLOCKS, BLOCK, 0, stream>>>(logit, target, weight, acc, cnt, out);
}

// Round 5
// 18.291 us; speedup vs baseline: 3.9797x; 3.9797x over previous
//
#include <hip/hip_runtime.h>

// SeeSawLoss, simplified:
//   loss(b,h,w) = log( sum_i exp(l[b,i,h,w]) * max(w[b,i], w[b,t]) ) - log(w[b,t]) - l[b,t,h,w]
//   out = mean over all (b,h,w)
// since M[i,t] = (wi > wt ? wi/wt : 1) == max(wi, wt)/wt.
// B=8, N=128, H=W=128. Timed replays are L3-resident (R4 counters), so this
// is a latency-hiding problem: 32 waves/CU, float2 loads, 16 loads in flight
// per wave. Target logit gathered once per pixel (not tracked per element).
// R4 lessons: no min-waves launch_bounds (VGPR strangulation), no shared-line
// atomics (two-kernel reduction instead).

#define B_    8
#define N_    128
#define HW_   16384              // 128*128
#define NPIX  (B_ * HW_)         // 131072
#define BLOCK 256
#define PX    64                 // pixels per block
#define OCTS  8                  // class octants
#define CPT   16                 // classes per thread
#define BLOCKS_PER_B (HW_ / PX)  // 256
#define NBLOCKS (B_ * BLOCKS_PER_B)  // 2048

__global__ __launch_bounds__(BLOCK) void seesaw_main(
    const float* __restrict__ logit,
    const int*   __restrict__ target,
    const float* __restrict__ weight,
    float*       __restrict__ partials)
{
    __shared__ float w_s[N_];
    __shared__ float sa[OCTS][PX];
    __shared__ int   t_s[PX];

    const int b    = blockIdx.x >> 8;            // / BLOCKS_PER_B
    const int pix0 = (blockIdx.x & 255) * PX;
    const int pp   = threadIdx.x & 31;           // pixel-pair index (2 px each)
    const int q    = threadIdx.x >> 5;           // class octant
    const int px   = pp * 2;                     // local pixel

    if (threadIdx.x < N_) w_s[threadIdx.x] = weight[b * N_ + threadIdx.x];
    __syncthreads();

    const int2 t2 = *(const int2*)(target + b * HW_ + pix0 + px);
    if (q == 0) *(int2*)&t_s[px] = t2;

    const float wt0 = w_s[t2.x];
    const float wt1 = w_s[t2.y];

    const int ibase = q * CPT;
    const float* lp = logit + (size_t)(b * N_ + ibase) * HW_ + pix0 + px;

    float a0 = 0.0f, a1 = 0.0f;

    #pragma unroll
    for (int k = 0; k < CPT; ++k) {
        const float2 l = *(const float2*)(lp + (size_t)k * HW_);
        const float wi = w_s[ibase + k];
        a0 = fmaf(__expf(l.x), fmaxf(wi, wt0), a0);
        a1 = fmaf(__expf(l.y), fmaxf(wi, wt1), a1);
    }

    *(float2*)&sa[q][px] = make_float2(a0, a1);
    __syncthreads();

    float loss = 0.0f;
    if (threadIdx.x < PX) {                      // wave 0: one lane per pixel
        const int p = threadIdx.x;
        float at = 0.0f;
        #pragma unroll
        for (int k = 0; k < OCTS; ++k) at += sa[k][p];
        const int   t  = t_s[p];
        const float wt = w_s[t];
        const float lt = logit[(size_t)(b * N_ + t) * HW_ + pix0 + p];  // L2-warm
        loss = __logf(at) - __logf(wt) - lt;

        #pragma unroll
        for (int o = 32; o > 0; o >>= 1) loss += __shfl_down(loss, o, 64);
    }
    if (threadIdx.x == 0) partials[blockIdx.x] = loss;
}

__global__ __launch_bounds__(1024) void seesaw_reduce(
    const float* __restrict__ partials,
    float*       __restrict__ out)
{
    __shared__ float red[16];
    float s = partials[threadIdx.x] + partials[threadIdx.x + 1024];

    #pragma unroll
    for (int o = 32; o > 0; o >>= 1) s += __shfl_down(s, o, 64);

    const int lane = threadIdx.x & 63;
    const int wid  = threadIdx.x >> 6;
    if (lane == 0) red[wid] = s;
    __syncthreads();

    if (threadIdx.x == 0) {
        float tot = 0.0f;
        #pragma unroll
        for (int k = 0; k < 16; ++k) tot += red[k];
        out[0] = tot * (1.0f / (float)NPIX);
    }
}

extern "C" void kernel_launch(void* const* d_in, const int* in_sizes, int n_in,
                              void* d_out, int out_size, void* d_ws, size_t ws_size,
                              hipStream_t stream)
{
    const float* logit  = (const float*)d_in[0];
    const int*   target = (const int*)  d_in[1];
    const float* weight = (const float*)d_in[2];
    // d_in[3] = epoch (unused by the reference math)

    float* partials = (float*)d_ws;   // NBLOCKS floats
    float* out      = (float*)d_out;

    seesaw_main<<<NBLOCKS, BLOCK, 0, stream>>>(logit, target, weight, partials);
    seesaw_reduce<<<1, 1024, 0, stream>>>(partials, out);
}